// Round 1
// baseline (515.721 us; speedup 1.0000x reference)
//
#include <hip/hip_runtime.h>
#include <math.h>

#define HID 16

// ---------- phase 1: degree (with self-loop) ----------
__global__ void k_init_deg(float* deg, int n) {
    int i = blockIdx.x * blockDim.x + threadIdx.x;
    if (i < n) deg[i] = 1.0f;   // self-loop
}

__global__ void k_deg_accum(const int* __restrict__ dstA, float* deg, int e) {
    int i = blockIdx.x * blockDim.x + threadIdx.x;
    if (i < e) atomicAdd(&deg[dstA[i]], 1.0f);
}

// deg -> dinv (in place), and layer-1 self-loop contribution s[n] = x[n]*dinv^2
__global__ void k_dinv_s(const float* __restrict__ x, float* deg_dinv,
                         float* s, int n) {
    int i = blockIdx.x * blockDim.x + threadIdx.x;
    if (i < n) {
        float d = rsqrtf(deg_dinv[i]);   // deg >= 1 always (self-loop)
        deg_dinv[i] = d;
        s[i] = x[i] * d * d;
    }
}

// ---------- phase 2: layer-1 scalar edge aggregation ----------
__global__ void k_s_edge(const int* __restrict__ srcA, const int* __restrict__ dstA,
                         const float* __restrict__ x, const float* __restrict__ dinv,
                         float* s, int e) {
    int i = blockIdx.x * blockDim.x + threadIdx.x;
    if (i < e) {
        int si = srcA[i], di = dstA[i];
        atomicAdd(&s[di], x[si] * dinv[si] * dinv[di]);
    }
}

// ---------- phase 3: per-node MLP: h1 = relu(s*W1 + b1); h2pre = h1 @ W2 ----------
// also initialize agg2 with the layer-2 self-loop contribution h2pre * dinv^2
__global__ void k_node_mlp(const float* __restrict__ s, const float* __restrict__ dinv,
                           const float* __restrict__ W1, const float* __restrict__ b1,
                           const float* __restrict__ W2, const float* __restrict__ b2,
                           float* __restrict__ h2pre, float* __restrict__ agg2, int n) {
    int i = blockIdx.x * blockDim.x + threadIdx.x;
    if (i >= n) return;
    float sv = s[i];
    float h1[HID];
#pragma unroll
    for (int j = 0; j < HID; ++j)
        h1[j] = fmaxf(sv * W1[j] + b1[j], 0.0f);
    float d2 = dinv[i] * dinv[i];
    float h2[HID];
#pragma unroll
    for (int k = 0; k < HID; ++k) {
        float acc = 0.0f;
#pragma unroll
        for (int j = 0; j < HID; ++j)
            acc = fmaf(h1[j], W2[j * HID + k], acc);
        h2[k] = acc;
    }
    float4* hp = (float4*)(h2pre + (size_t)i * HID);
    float4* ap = (float4*)(agg2 + (size_t)i * HID);
#pragma unroll
    for (int q = 0; q < 4; ++q) {
        float4 v = make_float4(h2[q*4+0], h2[q*4+1], h2[q*4+2], h2[q*4+3]);
        hp[q] = v;
        ap[q] = make_float4(v.x * d2, v.y * d2, v.z * d2, v.w * d2);
    }
}

// ---------- phase 4: layer-2 edge aggregation (16 lanes per edge) ----------
__global__ void k_agg_edge(const int* __restrict__ srcA, const int* __restrict__ dstA,
                           const float* __restrict__ dinv,
                           const float* __restrict__ h2pre,
                           float* __restrict__ agg2, int e) {
    int gid = blockIdx.x * blockDim.x + threadIdx.x;
    int ei = gid >> 4;
    int j  = gid & 15;
    if (ei < e) {
        int si = srcA[ei], di = dstA[ei];
        float w = dinv[si] * dinv[di];
        atomicAdd(&agg2[(size_t)di * HID + j], h2pre[(size_t)si * HID + j] * w);
    }
}

// ---------- phase 5: epilogue: out = tanh(relu(agg2 + b2) @ Wf + bf) ----------
__global__ void k_out(const float* __restrict__ agg2, const float* __restrict__ b2,
                      const float* __restrict__ Wf, const float* __restrict__ bf,
                      float* __restrict__ out, int n) {
    int i = blockIdx.x * blockDim.x + threadIdx.x;
    if (i >= n) return;
    float acc = bf[0];
#pragma unroll
    for (int k = 0; k < HID; ++k) {
        float h = fmaxf(agg2[(size_t)i * HID + k] + b2[k], 0.0f);
        acc = fmaf(h, Wf[k], acc);
    }
    out[i] = tanhf(acc);
}

extern "C" void kernel_launch(void* const* d_in, const int* in_sizes, int n_in,
                              void* d_out, int out_size, void* d_ws, size_t ws_size,
                              hipStream_t stream) {
    const float* x  = (const float*)d_in[0];
    const int*   ei = (const int*)d_in[1];   // [2, E] int32
    const float* W1 = (const float*)d_in[2];
    const float* b1 = (const float*)d_in[3];
    const float* W2 = (const float*)d_in[4];
    const float* b2 = (const float*)d_in[5];
    const float* Wf = (const float*)d_in[6];
    const float* bf = (const float*)d_in[7];
    float* out = (float*)d_out;

    const int N = in_sizes[0];       // 100000 (x is [N,1])
    const int E = in_sizes[1] / 2;   // 3200000

    const int* srcA = ei;
    const int* dstA = ei + E;

    // workspace layout (256B aligned blocks)
    char* ws = (char*)d_ws;
    size_t off = 0;
    auto take = [&](size_t bytes) -> char* {
        char* p = ws + off;
        off = (off + bytes + 255) & ~(size_t)255;
        return p;
    };
    float* dinv  = (float*)take((size_t)N * 4);        // deg then dinv (in place)
    float* s     = (float*)take((size_t)N * 4);        // layer-1 scalar agg
    float* h2pre = (float*)take((size_t)N * HID * 4);  // 6.4 MB
    float* agg2  = (float*)take((size_t)N * HID * 4);  // 6.4 MB
    (void)ws_size; (void)n_in; (void)out_size;

    const int B = 256;
    int nb_n = (N + B - 1) / B;
    int nb_e = (E + B - 1) / B;
    long long totD = (long long)E * HID;
    int nb_d = (int)((totD + B - 1) / B);

    hipLaunchKernelGGL(k_init_deg,  dim3(nb_n), dim3(B), 0, stream, dinv, N);
    hipLaunchKernelGGL(k_deg_accum, dim3(nb_e), dim3(B), 0, stream, dstA, dinv, E);
    hipLaunchKernelGGL(k_dinv_s,    dim3(nb_n), dim3(B), 0, stream, x, dinv, s, N);
    hipLaunchKernelGGL(k_s_edge,    dim3(nb_e), dim3(B), 0, stream, srcA, dstA, x, dinv, s, E);
    hipLaunchKernelGGL(k_node_mlp,  dim3(nb_n), dim3(B), 0, stream,
                       s, dinv, W1, b1, W2, b2, h2pre, agg2, N);
    hipLaunchKernelGGL(k_agg_edge,  dim3(nb_d), dim3(B), 0, stream,
                       srcA, dstA, dinv, h2pre, agg2, E);
    hipLaunchKernelGGL(k_out,       dim3(nb_n), dim3(B), 0, stream,
                       agg2, b2, Wf, bf, out, N);
}

// Round 3
// 503.930 us; speedup vs baseline: 1.0234x; 1.0234x over previous
//
#include <hip/hip_runtime.h>
#include <math.h>

#define HID 16
typedef unsigned int uint;

// ============================= CSR (sorted) path =============================

__global__ void k_hist(const int* __restrict__ dstA, uint* __restrict__ cnt, int e) {
    int i = blockIdx.x * blockDim.x + threadIdx.x;
    if (i < e) atomicAdd(&cnt[dstA[i]], 1u);
}

// exclusive scan over cnt -> rowStart. Valid for N <= 2048*256.
__global__ void k_scanA(const uint* __restrict__ cnt, uint* __restrict__ rowStart,
                        uint* __restrict__ blockSums, int n) {
    __shared__ uint lds[256];
    int base = blockIdx.x * 2048;
    int idx0 = base + threadIdx.x * 8;
    uint v[8]; uint tsum = 0;
#pragma unroll
    for (int k = 0; k < 8; ++k) {
        int i = idx0 + k;
        uint c = (i < n) ? cnt[i] : 0u;
        v[k] = tsum;
        tsum += c;
    }
    lds[threadIdx.x] = tsum;
    __syncthreads();
    for (int off = 1; off < 256; off <<= 1) {
        uint add = (threadIdx.x >= (uint)off) ? lds[threadIdx.x - off] : 0u;
        __syncthreads();
        lds[threadIdx.x] += add;
        __syncthreads();
    }
    uint texcl = (threadIdx.x == 0) ? 0u : lds[threadIdx.x - 1];
    if (threadIdx.x == 255) blockSums[blockIdx.x] = lds[255];
#pragma unroll
    for (int k = 0; k < 8; ++k) {
        int i = idx0 + k;
        if (i < n) rowStart[i] = texcl + v[k];
    }
}

__global__ void k_scanB(uint* __restrict__ blockSums, int nb) {
    if (blockIdx.x == 0 && threadIdx.x == 0) {
        uint acc = 0;
        for (int i = 0; i < nb; ++i) { uint v = blockSums[i]; blockSums[i] = acc; acc += v; }
    }
}

__global__ void k_scanC(uint* __restrict__ rowStart, const uint* __restrict__ blockSums, int n) {
    int i = blockIdx.x * 256 + threadIdx.x;
    if (i < n) rowStart[i] += blockSums[i >> 11];
}

__global__ void k_dinv_y(const float* __restrict__ x, const uint* __restrict__ cnt,
                         float* __restrict__ dinv, float* __restrict__ y, int n) {
    int i = blockIdx.x * blockDim.x + threadIdx.x;
    if (i < n) {
        float d = rsqrtf((float)(cnt[i] + 1u));   // +1 self-loop
        dinv[i] = d;
        y[i] = x[i] * d;
    }
}

// counting-sort scatter; mutates rowStart -> segment ENDS
__global__ void k_scatter(const int* __restrict__ srcA, const int* __restrict__ dstA,
                          uint* __restrict__ rowStart, int* __restrict__ srcSorted, int e) {
    int i = blockIdx.x * blockDim.x + threadIdx.x;
    if (i < e) {
        int d = dstA[i];
        uint pos = atomicAdd(&rowStart[d], 1u);
        srcSorted[pos] = srcA[i];
    }
}

// fused layer-1 gather + node MLP:
// s = dinv*(sum y[src] + y[i])   [self-loop: x*dinv^2 = dinv*y]
// h1 = relu(s*W1+b1);  g = (h1@W2)*dinv
__global__ void k_g1mlp(const uint* __restrict__ rowEnd, const int* __restrict__ srcSorted,
                        const float* __restrict__ y, const float* __restrict__ dinv,
                        const float* __restrict__ W1, const float* __restrict__ b1,
                        const float* __restrict__ W2,
                        float* __restrict__ g, int n) {
    int i = blockIdx.x * blockDim.x + threadIdx.x;
    if (i >= n) return;
    uint en = rowEnd[i];
    uint st = (i == 0) ? 0u : rowEnd[i - 1];
    float t = 0.0f;
    uint e = st;
    for (; e + 4 <= en; e += 4) {
        int s0 = srcSorted[e], s1 = srcSorted[e + 1], s2 = srcSorted[e + 2], s3 = srcSorted[e + 3];
        t += y[s0] + y[s1] + y[s2] + y[s3];
    }
    for (; e < en; ++e) t += y[srcSorted[e]];
    float d = dinv[i];
    float s = d * (t + y[i]);
    float h1[HID];
#pragma unroll
    for (int j = 0; j < HID; ++j)
        h1[j] = fmaxf(s * W1[j] + b1[j], 0.0f);
    float h2[HID];
#pragma unroll
    for (int k = 0; k < HID; ++k) {
        float acc = 0.0f;
#pragma unroll
        for (int j = 0; j < HID; ++j)
            acc = fmaf(h1[j], W2[j * HID + k], acc);
        h2[k] = acc * d;
    }
    float4* gp = (float4*)(g + (size_t)i * HID);
#pragma unroll
    for (int q = 0; q < 4; ++q)
        gp[q] = make_float4(h2[q * 4 + 0], h2[q * 4 + 1], h2[q * 4 + 2], h2[q * 4 + 3]);
}

// fused layer-2 gather + epilogue (16 lanes per node):
// agg2 = dinv*(sum g[src] + g[i])   [self-loop: h2pre*dinv^2 = dinv*g]
// out = tanh(relu(agg2+b2) @ Wf + bf)
__global__ void k_g2out(const uint* __restrict__ rowEnd, const int* __restrict__ srcSorted,
                        const float* __restrict__ g, const float* __restrict__ dinv,
                        const float* __restrict__ b2, const float* __restrict__ Wf,
                        const float* __restrict__ bf,
                        float* __restrict__ out, int n) {
    int gid = blockIdx.x * blockDim.x + threadIdx.x;
    int node = gid >> 4;
    int lane = gid & 15;
    if (node >= n) return;
    uint en = rowEnd[node];
    uint st = (node == 0) ? 0u : rowEnd[node - 1];
    float a = 0.0f;
    uint e = st;
    for (; e + 2 <= en; e += 2) {
        int s0 = srcSorted[e], s1 = srcSorted[e + 1];
        a += g[(size_t)s0 * HID + lane] + g[(size_t)s1 * HID + lane];
    }
    if (e < en) a += g[(size_t)srcSorted[e] * HID + lane];
    float d = dinv[node];
    float h = fmaxf(d * (a + g[(size_t)node * HID + lane]) + b2[lane], 0.0f);
    float v = h * Wf[lane];
#pragma unroll
    for (int m = 8; m >= 1; m >>= 1)
        v += __shfl_xor(v, m, 16);
    if (lane == 0) out[node] = tanhf(v + bf[0]);
}

// ============================= fallback (atomic) path =============================

__global__ void f_init_deg(float* deg, int n) {
    int i = blockIdx.x * blockDim.x + threadIdx.x;
    if (i < n) deg[i] = 1.0f;
}

__global__ void f_deg_accum(const int* __restrict__ dstA, float* deg, int e) {
    int i = blockIdx.x * blockDim.x + threadIdx.x;
    if (i < e) atomicAdd(&deg[dstA[i]], 1.0f);
}

__global__ void f_dinv_s(const float* __restrict__ x, float* deg_dinv, float* s, int n) {
    int i = blockIdx.x * blockDim.x + threadIdx.x;
    if (i < n) {
        float d = rsqrtf(deg_dinv[i]);
        deg_dinv[i] = d;
        s[i] = x[i] * d * d;
    }
}

__global__ void f_s_edge(const int* __restrict__ srcA, const int* __restrict__ dstA,
                         const float* __restrict__ x, const float* __restrict__ dinv,
                         float* s, int e) {
    int i = blockIdx.x * blockDim.x + threadIdx.x;
    if (i < e) {
        int si = srcA[i], di = dstA[i];
        atomicAdd(&s[di], x[si] * dinv[si] * dinv[di]);
    }
}

__global__ void f_node_mlp(const float* __restrict__ s, const float* __restrict__ dinv,
                           const float* __restrict__ W1, const float* __restrict__ b1,
                           const float* __restrict__ W2,
                           float* __restrict__ h2pre, float* __restrict__ agg2, int n) {
    int i = blockIdx.x * blockDim.x + threadIdx.x;
    if (i >= n) return;
    float sv = s[i];
    float h1[HID];
#pragma unroll
    for (int j = 0; j < HID; ++j)
        h1[j] = fmaxf(sv * W1[j] + b1[j], 0.0f);
    float d2 = dinv[i] * dinv[i];
    float h2[HID];
#pragma unroll
    for (int k = 0; k < HID; ++k) {
        float acc = 0.0f;
#pragma unroll
        for (int j = 0; j < HID; ++j)
            acc = fmaf(h1[j], W2[j * HID + k], acc);
        h2[k] = acc;
    }
    float4* hp = (float4*)(h2pre + (size_t)i * HID);
    float4* ap = (float4*)(agg2 + (size_t)i * HID);
#pragma unroll
    for (int q = 0; q < 4; ++q) {
        float4 v = make_float4(h2[q*4+0], h2[q*4+1], h2[q*4+2], h2[q*4+3]);
        hp[q] = v;
        ap[q] = make_float4(v.x * d2, v.y * d2, v.z * d2, v.w * d2);
    }
}

__global__ void f_agg_edge(const int* __restrict__ srcA, const int* __restrict__ dstA,
                           const float* __restrict__ dinv,
                           const float* __restrict__ h2pre,
                           float* __restrict__ agg2, int e) {
    int gid = blockIdx.x * blockDim.x + threadIdx.x;
    int ei = gid >> 4;
    int j  = gid & 15;
    if (ei < e) {
        int si = srcA[ei], di = dstA[ei];
        float w = dinv[si] * dinv[di];
        atomicAdd(&agg2[(size_t)di * HID + j], h2pre[(size_t)si * HID + j] * w);
    }
}

__global__ void f_out(const float* __restrict__ agg2, const float* __restrict__ b2,
                      const float* __restrict__ Wf, const float* __restrict__ bf,
                      float* __restrict__ out, int n) {
    int i = blockIdx.x * blockDim.x + threadIdx.x;
    if (i >= n) return;
    float acc = bf[0];
#pragma unroll
    for (int k = 0; k < HID; ++k) {
        float h = fmaxf(agg2[(size_t)i * HID + k] + b2[k], 0.0f);
        acc = fmaf(h, Wf[k], acc);
    }
    out[i] = tanhf(acc);
}

// ============================= launch =============================

extern "C" void kernel_launch(void* const* d_in, const int* in_sizes, int n_in,
                              void* d_out, int out_size, void* d_ws, size_t ws_size,
                              hipStream_t stream) {
    const float* x  = (const float*)d_in[0];
    const int*   ei = (const int*)d_in[1];
    const float* W1 = (const float*)d_in[2];
    const float* b1 = (const float*)d_in[3];
    const float* W2 = (const float*)d_in[4];
    const float* b2 = (const float*)d_in[5];
    const float* Wf = (const float*)d_in[6];
    const float* bf = (const float*)d_in[7];
    float* out = (float*)d_out;

    const int N = in_sizes[0];
    const int E = in_sizes[1] / 2;
    const int* srcA = ei;
    const int* dstA = ei + E;

    const int B = 256;
    int nb_n = (N + B - 1) / B;
    int nb_e = (E + B - 1) / B;
    (void)n_in; (void)out_size;

    // ---- CSR layout ----
    size_t off = 0;
    auto takeo = [&](size_t bytes) -> size_t {
        size_t p = off;
        off = (off + bytes + 255) & ~(size_t)255;
        return p;
    };
    size_t o_cnt  = takeo((size_t)N * 4);
    size_t o_row  = takeo((size_t)N * 4);
    size_t o_bsum = takeo(1024);
    size_t o_dinv = takeo((size_t)N * 4);
    size_t o_y    = takeo((size_t)N * 4);
    size_t o_ss   = takeo((size_t)E * 4);
    size_t o_g    = takeo((size_t)N * HID * 4);
    size_t need_csr = off;

    if (ws_size >= need_csr && N <= 2048 * 256) {
        char* ws = (char*)d_ws;
        uint*  cnt       = (uint*)(ws + o_cnt);
        uint*  rowEnd    = (uint*)(ws + o_row);   // starts, then ends after scatter
        uint*  blockSums = (uint*)(ws + o_bsum);
        float* dinv      = (float*)(ws + o_dinv);
        float* y         = (float*)(ws + o_y);
        int*   srcSorted = (int*)(ws + o_ss);
        float* g         = (float*)(ws + o_g);

        int nb_scanA = (N + 2047) / 2048;
        int nb_g2 = ((N * HID) + B - 1) / B;

        hipMemsetAsync(cnt, 0, (size_t)N * 4, stream);
        hipLaunchKernelGGL(k_hist,    dim3(nb_e), dim3(B), 0, stream, dstA, cnt, E);
        hipLaunchKernelGGL(k_scanA,   dim3(nb_scanA), dim3(B), 0, stream, cnt, rowEnd, blockSums, N);
        hipLaunchKernelGGL(k_scanB,   dim3(1), dim3(64), 0, stream, blockSums, nb_scanA);
        hipLaunchKernelGGL(k_scanC,   dim3(nb_n), dim3(B), 0, stream, rowEnd, blockSums, N);
        hipLaunchKernelGGL(k_dinv_y,  dim3(nb_n), dim3(B), 0, stream, x, cnt, dinv, y, N);
        hipLaunchKernelGGL(k_scatter, dim3(nb_e), dim3(B), 0, stream, srcA, dstA, rowEnd, srcSorted, E);
        hipLaunchKernelGGL(k_g1mlp,   dim3(nb_n), dim3(B), 0, stream,
                           rowEnd, srcSorted, y, dinv, W1, b1, W2, g, N);
        hipLaunchKernelGGL(k_g2out,   dim3(nb_g2), dim3(B), 0, stream,
                           rowEnd, srcSorted, g, dinv, b2, Wf, bf, out, N);
    } else {
        // ---- fallback: known-good atomic path ----
        size_t foff = 0;
        auto ftake = [&](size_t bytes) -> size_t {
            size_t p = foff;
            foff = (foff + bytes + 255) & ~(size_t)255;
            return p;
        };
        char* ws = (char*)d_ws;
        float* dinv  = (float*)(ws + ftake((size_t)N * 4));
        float* s     = (float*)(ws + ftake((size_t)N * 4));
        float* h2pre = (float*)(ws + ftake((size_t)N * HID * 4));
        float* agg2  = (float*)(ws + ftake((size_t)N * HID * 4));

        long long totD = (long long)E * HID;
        int nb_d = (int)((totD + B - 1) / B);

        hipLaunchKernelGGL(f_init_deg,  dim3(nb_n), dim3(B), 0, stream, dinv, N);
        hipLaunchKernelGGL(f_deg_accum, dim3(nb_e), dim3(B), 0, stream, dstA, dinv, E);
        hipLaunchKernelGGL(f_dinv_s,    dim3(nb_n), dim3(B), 0, stream, x, dinv, s, N);
        hipLaunchKernelGGL(f_s_edge,    dim3(nb_e), dim3(B), 0, stream, srcA, dstA, x, dinv, s, E);
        hipLaunchKernelGGL(f_node_mlp,  dim3(nb_n), dim3(B), 0, stream,
                           s, dinv, W1, b1, W2, h2pre, agg2, N);
        hipLaunchKernelGGL(f_agg_edge,  dim3(nb_d), dim3(B), 0, stream,
                           srcA, dstA, dinv, h2pre, agg2, E);
        hipLaunchKernelGGL(f_out,       dim3(nb_n), dim3(B), 0, stream,
                           agg2, b2, Wf, bf, out, N);
    }
}

// Round 4
// 455.860 us; speedup vs baseline: 1.1313x; 1.1055x over previous
//
#include <hip/hip_runtime.h>
#include <math.h>

#define HID 16
typedef unsigned int uint;

#define PSHIFT 7            // 128 nodes per bucket
#define PSIZE  128
#define PMASK  127
#define SRCBITS 17          // supports N <= 131072
#define SRCMASK 0x1FFFFu
#define PAD 16              // uints between atomic counters (64B anti-contention)
#define TILE 8192           // edges per partition tile
#define MAXNB 1024          // max buckets (N <= 131072)

// ============================= fast path: LDS multisplit =============================

// ---- pass 1: per-bucket edge counts ----
__global__ void p_bcount(const int* __restrict__ dstA, uint* __restrict__ cntPad,
                         int e, int nb) {
    __shared__ uint hist[MAXNB];
    int t = threadIdx.x;
    for (int i = t; i < nb; i += 256) hist[i] = 0;
    __syncthreads();
    int base = blockIdx.x * TILE;
#pragma unroll
    for (int k = 0; k < TILE / 256; ++k) {
        int idx = base + k * 256 + t;
        if (idx < e) atomicAdd(&hist[((uint)dstA[idx]) >> PSHIFT], 1u);
    }
    __syncthreads();
    for (int i = t; i < nb; i += 256) {
        uint c = hist[i];
        if (c) atomicAdd(&cntPad[i * PAD], c);
    }
}

// ---- pass 2: exclusive scan of bucket counts; init global cursors ----
__global__ void p_bscan(const uint* __restrict__ cntPad, uint* __restrict__ cursorPad,
                        uint* __restrict__ bBase, uint* __restrict__ bCnt, int nb) {
    __shared__ uint tsum[256];
    int t = threadIdx.x;
    uint loc[4]; uint s = 0;
#pragma unroll
    for (int k = 0; k < 4; ++k) {
        int i = t * 4 + k;
        uint c = (i < nb) ? cntPad[i * PAD] : 0u;
        loc[k] = s; s += c;
    }
    tsum[t] = s;
    __syncthreads();
    for (int off = 1; off < 256; off <<= 1) {
        uint v = (t >= off) ? tsum[t - off] : 0u;
        __syncthreads();
        tsum[t] += v;
        __syncthreads();
    }
    uint excl = (t == 0) ? 0u : tsum[t - 1];
#pragma unroll
    for (int k = 0; k < 4; ++k) {
        int i = t * 4 + k;
        if (i < nb) {
            uint c = cntPad[i * PAD];
            uint b = excl + loc[k];
            bBase[i] = b; bCnt[i] = c; cursorPad[i * PAD] = b;
        }
    }
}

// ---- pass 3: partition edges into dst-buckets (LDS multisplit per tile) ----
__global__ void p_part(const int* __restrict__ srcA, const int* __restrict__ dstA,
                       uint* __restrict__ cursorPad, uint* __restrict__ part,
                       int e, int nb) {
    __shared__ uint payload[TILE];      // 32 KB
    __shared__ uint hist[MAXNB];
    __shared__ uint binStart[MAXNB];
    __shared__ uint cursorL[MAXNB];
    __shared__ uint gdelta[MAXNB];
    __shared__ uint tsum[256];
    int t = threadIdx.x;
    for (int i = t; i < nb; i += 256) hist[i] = 0;
    __syncthreads();
    int base = blockIdx.x * TILE;
    // phase A: tile histogram over dst
#pragma unroll
    for (int k = 0; k < TILE / 256; ++k) {
        int idx = base + k * 256 + t;
        if (idx < e) atomicAdd(&hist[((uint)dstA[idx]) >> PSHIFT], 1u);
    }
    __syncthreads();
    // phase B: scan -> binStart; reserve global space per bucket
    uint loc[4]; uint s = 0;
#pragma unroll
    for (int k = 0; k < 4; ++k) {
        int i = t * 4 + k;
        uint c = (i < nb) ? hist[i] : 0u;
        loc[k] = s; s += c;
    }
    tsum[t] = s;
    __syncthreads();
    for (int off = 1; off < 256; off <<= 1) {
        uint v = (t >= off) ? tsum[t - off] : 0u;
        __syncthreads();
        tsum[t] += v;
        __syncthreads();
    }
    uint excl = (t == 0) ? 0u : tsum[t - 1];
#pragma unroll
    for (int k = 0; k < 4; ++k) {
        int i = t * 4 + k;
        if (i < nb) {
            uint bs = excl + loc[k];
            binStart[i] = bs; cursorL[i] = bs;
            uint c = hist[i];
            if (c) gdelta[i] = atomicAdd(&cursorPad[i * PAD], c) - bs;
        }
    }
    __syncthreads();
    // phase C: scatter packed words into LDS, grouped by bucket
#pragma unroll
    for (int k = 0; k < TILE / 256; ++k) {
        int idx = base + k * 256 + t;
        if (idx < e) {
            uint d = (uint)dstA[idx];
            uint w = ((d & PMASK) << SRCBITS) | (uint)srcA[idx];
            uint bk = d >> PSHIFT;
            uint pos = atomicAdd(&cursorL[bk], 1u);
            payload[pos] = w;
        }
    }
    __syncthreads();
    // phase D: flush contiguous runs to global
    for (int bk = t; bk < nb; bk += 256) {
        uint c = hist[bk];
        if (!c) continue;
        uint st = binStart[bk];
        uint gd = gdelta[bk];
        for (uint i = 0; i < c; ++i)
            part[gd + st + i] = payload[st + i];
    }
}

// ---- pass 4: per-bucket degree -> dinv, y = x*dinv ----
__global__ void p_degy(const uint* __restrict__ part, const uint* __restrict__ bBase,
                       const uint* __restrict__ bCnt, const float* __restrict__ x,
                       float* __restrict__ dinv, float* __restrict__ y, int n) {
    __shared__ uint cnts[PSIZE];
    int b = blockIdx.x, t = threadIdx.x;
    if (t < PSIZE) cnts[t] = 0;
    __syncthreads();
    uint base = bBase[b], cnt = bCnt[b];
#pragma unroll 4
    for (uint i = base + t; i < base + cnt; i += 256)
        atomicAdd(&cnts[part[i] >> SRCBITS], 1u);
    __syncthreads();
    if (t < PSIZE) {
        int node = b * PSIZE + t;
        if (node < n) {
            float d = rsqrtf((float)(cnts[t] + 1u));   // +1 self-loop
            dinv[node] = d;
            y[node] = x[node] * d;
        }
    }
}

// ---- pass 5: layer-1 aggregate + fused MLP -> g = (relu(s*W1+b1)@W2)*dinv ----
__global__ void p_agg1(const uint* __restrict__ part, const uint* __restrict__ bBase,
                       const uint* __restrict__ bCnt, const float* __restrict__ y,
                       const float* __restrict__ dinv,
                       const float* __restrict__ W1, const float* __restrict__ b1,
                       const float* __restrict__ W2,
                       float* __restrict__ g, int n) {
    __shared__ float acc[PSIZE];
    int b = blockIdx.x, t = threadIdx.x;
    if (t < PSIZE) acc[t] = 0.0f;
    __syncthreads();
    uint base = bBase[b], cnt = bCnt[b];
#pragma unroll 4
    for (uint i = base + t; i < base + cnt; i += 256) {
        uint w = part[i];
        atomicAdd(&acc[w >> SRCBITS], y[w & SRCMASK]);
    }
    __syncthreads();
    if (t < PSIZE) {
        int node = b * PSIZE + t;
        if (node < n) {
            float d = dinv[node];
            float sv = d * (acc[t] + y[node]);   // self-loop: x*dinv^2 = dinv*y
            float h1[HID], h2[HID];
#pragma unroll
            for (int j = 0; j < HID; ++j)
                h1[j] = fmaxf(sv * W1[j] + b1[j], 0.0f);
#pragma unroll
            for (int k = 0; k < HID; ++k) {
                float a = 0.0f;
#pragma unroll
                for (int j = 0; j < HID; ++j)
                    a = fmaf(h1[j], W2[j * HID + k], a);
                h2[k] = a * d;
            }
            float4* gp = (float4*)(g + (size_t)node * HID);
#pragma unroll
            for (int q = 0; q < 4; ++q)
                gp[q] = make_float4(h2[q*4+0], h2[q*4+1], h2[q*4+2], h2[q*4+3]);
        }
    }
}

// ---- pass 6: layer-2 aggregate (16 lanes/edge) + fused epilogue -> out ----
__global__ void p_agg2(const uint* __restrict__ part, const uint* __restrict__ bBase,
                       const uint* __restrict__ bCnt, const float* __restrict__ g,
                       const float* __restrict__ dinv,
                       const float* __restrict__ b2, const float* __restrict__ Wf,
                       const float* __restrict__ bf,
                       float* __restrict__ out, int n) {
    __shared__ float acc[PSIZE][HID + 1];   // +1 pad: breaks 32-way bank conflict
    int b = blockIdx.x, t = threadIdx.x;
    if (t < PSIZE) {
        int node = b * PSIZE + t;
        if (node < n) {
            const float4* gp = (const float4*)(g + (size_t)node * HID);
#pragma unroll
            for (int q = 0; q < 4; ++q) {
                float4 v = gp[q];
                acc[t][q*4+0] = v.x; acc[t][q*4+1] = v.y;
                acc[t][q*4+2] = v.z; acc[t][q*4+3] = v.w;
            }
        } else {
#pragma unroll
            for (int j = 0; j < HID; ++j) acc[t][j] = 0.0f;
        }
    }
    __syncthreads();
    uint base = bBase[b], cnt = bCnt[b];
    int eg = t >> 4, lane = t & 15;
#pragma unroll 2
    for (uint i = base + eg; i < base + cnt; i += 16) {
        uint w = part[i];                    // broadcast within 16-lane group
        uint src = w & SRCMASK;
        uint dl = w >> SRCBITS;
        atomicAdd(&acc[dl][lane], g[(size_t)src * HID + lane]);  // 64B line gather
    }
    __syncthreads();
    if (t < PSIZE) {
        int node = b * PSIZE + t;
        if (node < n) {
            float d = dinv[node];
            float o = bf[0];
#pragma unroll
            for (int j = 0; j < HID; ++j) {
                float h = fmaxf(fmaf(d, acc[t][j], b2[j]), 0.0f);
                o = fmaf(h, Wf[j], o);
            }
            out[node] = tanhf(o);
        }
    }
}

// ============================= fallback (atomic) path =============================

__global__ void f_init_deg(float* deg, int n) {
    int i = blockIdx.x * blockDim.x + threadIdx.x;
    if (i < n) deg[i] = 1.0f;
}

__global__ void f_deg_accum(const int* __restrict__ dstA, float* deg, int e) {
    int i = blockIdx.x * blockDim.x + threadIdx.x;
    if (i < e) atomicAdd(&deg[dstA[i]], 1.0f);
}

__global__ void f_dinv_s(const float* __restrict__ x, float* deg_dinv, float* s, int n) {
    int i = blockIdx.x * blockDim.x + threadIdx.x;
    if (i < n) {
        float d = rsqrtf(deg_dinv[i]);
        deg_dinv[i] = d;
        s[i] = x[i] * d * d;
    }
}

__global__ void f_s_edge(const int* __restrict__ srcA, const int* __restrict__ dstA,
                         const float* __restrict__ x, const float* __restrict__ dinv,
                         float* s, int e) {
    int i = blockIdx.x * blockDim.x + threadIdx.x;
    if (i < e) {
        int si = srcA[i], di = dstA[i];
        atomicAdd(&s[di], x[si] * dinv[si] * dinv[di]);
    }
}

__global__ void f_node_mlp(const float* __restrict__ s, const float* __restrict__ dinv,
                           const float* __restrict__ W1, const float* __restrict__ b1,
                           const float* __restrict__ W2,
                           float* __restrict__ h2pre, float* __restrict__ agg2, int n) {
    int i = blockIdx.x * blockDim.x + threadIdx.x;
    if (i >= n) return;
    float sv = s[i];
    float h1[HID];
#pragma unroll
    for (int j = 0; j < HID; ++j)
        h1[j] = fmaxf(sv * W1[j] + b1[j], 0.0f);
    float d2 = dinv[i] * dinv[i];
    float h2[HID];
#pragma unroll
    for (int k = 0; k < HID; ++k) {
        float acc = 0.0f;
#pragma unroll
        for (int j = 0; j < HID; ++j)
            acc = fmaf(h1[j], W2[j * HID + k], acc);
        h2[k] = acc;
    }
    float4* hp = (float4*)(h2pre + (size_t)i * HID);
    float4* ap = (float4*)(agg2 + (size_t)i * HID);
#pragma unroll
    for (int q = 0; q < 4; ++q) {
        float4 v = make_float4(h2[q*4+0], h2[q*4+1], h2[q*4+2], h2[q*4+3]);
        hp[q] = v;
        ap[q] = make_float4(v.x * d2, v.y * d2, v.z * d2, v.w * d2);
    }
}

__global__ void f_agg_edge(const int* __restrict__ srcA, const int* __restrict__ dstA,
                           const float* __restrict__ dinv,
                           const float* __restrict__ h2pre,
                           float* __restrict__ agg2, int e) {
    int gid = blockIdx.x * blockDim.x + threadIdx.x;
    int ei = gid >> 4;
    int j  = gid & 15;
    if (ei < e) {
        int si = srcA[ei], di = dstA[ei];
        float w = dinv[si] * dinv[di];
        atomicAdd(&agg2[(size_t)di * HID + j], h2pre[(size_t)si * HID + j] * w);
    }
}

__global__ void f_out(const float* __restrict__ agg2, const float* __restrict__ b2,
                      const float* __restrict__ Wf, const float* __restrict__ bf,
                      float* __restrict__ out, int n) {
    int i = blockIdx.x * blockDim.x + threadIdx.x;
    if (i >= n) return;
    float acc = bf[0];
#pragma unroll
    for (int k = 0; k < HID; ++k) {
        float h = fmaxf(agg2[(size_t)i * HID + k] + b2[k], 0.0f);
        acc = fmaf(h, Wf[k], acc);
    }
    out[i] = tanhf(acc);
}

// ============================= launch =============================

extern "C" void kernel_launch(void* const* d_in, const int* in_sizes, int n_in,
                              void* d_out, int out_size, void* d_ws, size_t ws_size,
                              hipStream_t stream) {
    const float* x  = (const float*)d_in[0];
    const int*   ei = (const int*)d_in[1];
    const float* W1 = (const float*)d_in[2];
    const float* b1 = (const float*)d_in[3];
    const float* W2 = (const float*)d_in[4];
    const float* b2 = (const float*)d_in[5];
    const float* Wf = (const float*)d_in[6];
    const float* bf = (const float*)d_in[7];
    float* out = (float*)d_out;

    const int N = in_sizes[0];
    const int E = in_sizes[1] / 2;
    const int* srcA = ei;
    const int* dstA = ei + E;
    (void)n_in; (void)out_size;

    const int NB = (N + PMASK) >> PSHIFT;
    const int B = 256;
    int nb_n = (N + B - 1) / B;
    int nb_e = (E + B - 1) / B;
    int tiles = (E + TILE - 1) / TILE;

    // fast-path ws layout
    size_t off = 0;
    auto takeo = [&](size_t bytes) -> size_t {
        size_t p = off;
        off = (off + bytes + 255) & ~(size_t)255;
        return p;
    };
    size_t o_cntp = takeo((size_t)NB * PAD * 4);
    size_t o_curp = takeo((size_t)NB * PAD * 4);
    size_t o_bb   = takeo((size_t)NB * 4);
    size_t o_bc   = takeo((size_t)NB * 4);
    size_t o_dinv = takeo((size_t)N * 4);
    size_t o_y    = takeo((size_t)N * 4);
    size_t o_part = takeo((size_t)E * 4);
    size_t o_g    = takeo((size_t)N * HID * 4);
    size_t need = off;

    if (N <= (1 << SRCBITS) && ws_size >= need) {
        char* ws = (char*)d_ws;
        uint*  cntPad    = (uint*)(ws + o_cntp);
        uint*  cursorPad = (uint*)(ws + o_curp);
        uint*  bBase     = (uint*)(ws + o_bb);
        uint*  bCnt      = (uint*)(ws + o_bc);
        float* dinv      = (float*)(ws + o_dinv);
        float* y         = (float*)(ws + o_y);
        uint*  part      = (uint*)(ws + o_part);
        float* g         = (float*)(ws + o_g);

        hipMemsetAsync(cntPad, 0, (size_t)NB * PAD * 4, stream);
        hipLaunchKernelGGL(p_bcount, dim3(tiles), dim3(B), 0, stream, dstA, cntPad, E, NB);
        hipLaunchKernelGGL(p_bscan,  dim3(1), dim3(B), 0, stream, cntPad, cursorPad, bBase, bCnt, NB);
        hipLaunchKernelGGL(p_part,   dim3(tiles), dim3(B), 0, stream, srcA, dstA, cursorPad, part, E, NB);
        hipLaunchKernelGGL(p_degy,   dim3(NB), dim3(B), 0, stream, part, bBase, bCnt, x, dinv, y, N);
        hipLaunchKernelGGL(p_agg1,   dim3(NB), dim3(B), 0, stream, part, bBase, bCnt, y, dinv, W1, b1, W2, g, N);
        hipLaunchKernelGGL(p_agg2,   dim3(NB), dim3(B), 0, stream, part, bBase, bCnt, g, dinv, b2, Wf, bf, out, N);
    } else {
        // fallback: known-good atomic path
        size_t foff = 0;
        auto ftake = [&](size_t bytes) -> size_t {
            size_t p = foff;
            foff = (foff + bytes + 255) & ~(size_t)255;
            return p;
        };
        char* ws = (char*)d_ws;
        float* dinv  = (float*)(ws + ftake((size_t)N * 4));
        float* s     = (float*)(ws + ftake((size_t)N * 4));
        float* h2pre = (float*)(ws + ftake((size_t)N * HID * 4));
        float* agg2  = (float*)(ws + ftake((size_t)N * HID * 4));

        long long totD = (long long)E * HID;
        int nb_d = (int)((totD + B - 1) / B);

        hipLaunchKernelGGL(f_init_deg,  dim3(nb_n), dim3(B), 0, stream, dinv, N);
        hipLaunchKernelGGL(f_deg_accum, dim3(nb_e), dim3(B), 0, stream, dstA, dinv, E);
        hipLaunchKernelGGL(f_dinv_s,    dim3(nb_n), dim3(B), 0, stream, x, dinv, s, N);
        hipLaunchKernelGGL(f_s_edge,    dim3(nb_e), dim3(B), 0, stream, srcA, dstA, x, dinv, s, E);
        hipLaunchKernelGGL(f_node_mlp,  dim3(nb_n), dim3(B), 0, stream,
                           s, dinv, W1, b1, W2, h2pre, agg2, N);
        hipLaunchKernelGGL(f_agg_edge,  dim3(nb_d), dim3(B), 0, stream,
                           srcA, dstA, dinv, h2pre, agg2, E);
        hipLaunchKernelGGL(f_out,       dim3(nb_n), dim3(B), 0, stream,
                           agg2, b2, Wf, bf, out, N);
    }
}

// Round 5
// 445.195 us; speedup vs baseline: 1.1584x; 1.0240x over previous
//
#include <hip/hip_runtime.h>
#include <math.h>

#define HID 16
typedef unsigned int uint;

#define PSHIFT 7            // 128 nodes per bucket
#define PSIZE  128
#define PMASK  127
#define SRCBITS 17          // supports N <= 131072
#define SRCMASK 0x1FFFFu
#define PAD 16              // uints between atomic counters (64B anti-contention)
#define TILE 8192           // edges per partition tile
#define MAXNB 1024          // max buckets (N <= 131072)
#define AGT 1024            // threads for aggregation kernels

// ============================= fast path: LDS multisplit =============================

// ---- pass 1: per-bucket edge counts ----
__global__ void p_bcount(const int* __restrict__ dstA, uint* __restrict__ cntPad,
                         int e, int nb) {
    __shared__ uint hist[MAXNB];
    int t = threadIdx.x;
    for (int i = t; i < nb; i += 256) hist[i] = 0;
    __syncthreads();
    int base = blockIdx.x * TILE;
#pragma unroll
    for (int k = 0; k < TILE / 256; ++k) {
        int idx = base + k * 256 + t;
        if (idx < e) atomicAdd(&hist[((uint)dstA[idx]) >> PSHIFT], 1u);
    }
    __syncthreads();
    for (int i = t; i < nb; i += 256) {
        uint c = hist[i];
        if (c) atomicAdd(&cntPad[i * PAD], c);
    }
}

// ---- pass 2: exclusive scan of bucket counts; init global cursors ----
__global__ void p_bscan(const uint* __restrict__ cntPad, uint* __restrict__ cursorPad,
                        uint* __restrict__ bBase, uint* __restrict__ bCnt, int nb) {
    __shared__ uint tsum[256];
    int t = threadIdx.x;
    uint loc[4]; uint s = 0;
#pragma unroll
    for (int k = 0; k < 4; ++k) {
        int i = t * 4 + k;
        uint c = (i < nb) ? cntPad[i * PAD] : 0u;
        loc[k] = s; s += c;
    }
    tsum[t] = s;
    __syncthreads();
    for (int off = 1; off < 256; off <<= 1) {
        uint v = (t >= off) ? tsum[t - off] : 0u;
        __syncthreads();
        tsum[t] += v;
        __syncthreads();
    }
    uint excl = (t == 0) ? 0u : tsum[t - 1];
#pragma unroll
    for (int k = 0; k < 4; ++k) {
        int i = t * 4 + k;
        if (i < nb) {
            uint c = cntPad[i * PAD];
            uint b = excl + loc[k];
            bBase[i] = b; bCnt[i] = c; cursorPad[i * PAD] = b;
        }
    }
}

// ---- pass 3: partition edges into dst-buckets (LDS multisplit per tile) ----
__global__ void p_part(const int* __restrict__ srcA, const int* __restrict__ dstA,
                       uint* __restrict__ cursorPad, uint* __restrict__ part,
                       int e, int nb) {
    __shared__ uint payload[TILE];      // 32 KB
    __shared__ uint hist[MAXNB];
    __shared__ uint binStart[MAXNB];
    __shared__ uint cursorL[MAXNB];
    __shared__ uint gdelta[MAXNB];
    __shared__ uint tsum[256];
    int t = threadIdx.x;
    for (int i = t; i < nb; i += 256) hist[i] = 0;
    __syncthreads();
    int base = blockIdx.x * TILE;
    // phase A: tile histogram over dst
#pragma unroll
    for (int k = 0; k < TILE / 256; ++k) {
        int idx = base + k * 256 + t;
        if (idx < e) atomicAdd(&hist[((uint)dstA[idx]) >> PSHIFT], 1u);
    }
    __syncthreads();
    // phase B: scan -> binStart; reserve global space per bucket
    uint loc[4]; uint s = 0;
#pragma unroll
    for (int k = 0; k < 4; ++k) {
        int i = t * 4 + k;
        uint c = (i < nb) ? hist[i] : 0u;
        loc[k] = s; s += c;
    }
    tsum[t] = s;
    __syncthreads();
    for (int off = 1; off < 256; off <<= 1) {
        uint v = (t >= off) ? tsum[t - off] : 0u;
        __syncthreads();
        tsum[t] += v;
        __syncthreads();
    }
    uint excl = (t == 0) ? 0u : tsum[t - 1];
#pragma unroll
    for (int k = 0; k < 4; ++k) {
        int i = t * 4 + k;
        if (i < nb) {
            uint bs = excl + loc[k];
            binStart[i] = bs; cursorL[i] = bs;
            uint c = hist[i];
            if (c) gdelta[i] = atomicAdd(&cursorPad[i * PAD], c) - bs;
        }
    }
    __syncthreads();
    // phase C: scatter packed words into LDS, grouped by bucket
#pragma unroll
    for (int k = 0; k < TILE / 256; ++k) {
        int idx = base + k * 256 + t;
        if (idx < e) {
            uint d = (uint)dstA[idx];
            uint w = ((d & PMASK) << SRCBITS) | (uint)srcA[idx];
            uint bk = d >> PSHIFT;
            uint pos = atomicAdd(&cursorL[bk], 1u);
            payload[pos] = w;
        }
    }
    __syncthreads();
    // phase D: flush contiguous runs to global (16-lane groups cooperate per run)
    int grp = t >> 4, lane16 = t & 15;
    for (int bk = grp; bk < nb; bk += 16) {
        uint c = hist[bk];
        if (!c) continue;
        uint st = binStart[bk];
        uint gd = gdelta[bk];
        for (uint i = lane16; i < c; i += 16)
            part[gd + st + i] = payload[st + i];
    }
}

// ---- pass 4: per-bucket degree -> dinv, y = x*dinv ----
__global__ __launch_bounds__(AGT)
void p_degy(const uint* __restrict__ part, const uint* __restrict__ bBase,
            const uint* __restrict__ bCnt, const float* __restrict__ x,
            float* __restrict__ dinv, float* __restrict__ y, int n) {
    __shared__ uint cnts[PSIZE];
    int b = blockIdx.x, t = threadIdx.x;
    if (t < PSIZE) cnts[t] = 0;
    __syncthreads();
    uint base = bBase[b], cnt = bCnt[b];
    for (uint i = base + t; i < base + cnt; i += AGT)
        atomicAdd(&cnts[part[i] >> SRCBITS], 1u);
    __syncthreads();
    if (t < PSIZE) {
        int node = b * PSIZE + t;
        if (node < n) {
            float d = rsqrtf((float)(cnts[t] + 1u));   // +1 self-loop
            dinv[node] = d;
            y[node] = x[node] * d;
        }
    }
}

// ---- pass 5: layer-1 aggregate + fused MLP -> g = (relu(s*W1+b1)@W2)*dinv ----
__global__ __launch_bounds__(AGT)
void p_agg1(const uint* __restrict__ part, const uint* __restrict__ bBase,
            const uint* __restrict__ bCnt, const float* __restrict__ y,
            const float* __restrict__ dinv,
            const float* __restrict__ W1, const float* __restrict__ b1,
            const float* __restrict__ W2,
            float* __restrict__ g, int n) {
    __shared__ float acc[PSIZE];
    int b = blockIdx.x, t = threadIdx.x;
    if (t < PSIZE) acc[t] = 0.0f;
    __syncthreads();
    uint base = bBase[b], cnt = bCnt[b];
    for (uint i = base + t; i < base + cnt; i += AGT) {
        uint w = part[i];
        atomicAdd(&acc[w >> SRCBITS], y[w & SRCMASK]);
    }
    __syncthreads();
    if (t < PSIZE) {
        int node = b * PSIZE + t;
        if (node < n) {
            float d = dinv[node];
            float sv = d * (acc[t] + y[node]);   // self-loop: x*dinv^2 = dinv*y
            float h1[HID], h2[HID];
#pragma unroll
            for (int j = 0; j < HID; ++j)
                h1[j] = fmaxf(sv * W1[j] + b1[j], 0.0f);
#pragma unroll
            for (int k = 0; k < HID; ++k) {
                float a = 0.0f;
#pragma unroll
                for (int j = 0; j < HID; ++j)
                    a = fmaf(h1[j], W2[j * HID + k], a);
                h2[k] = a * d;
            }
            float4* gp = (float4*)(g + (size_t)node * HID);
#pragma unroll
            for (int q = 0; q < 4; ++q)
                gp[q] = make_float4(h2[q*4+0], h2[q*4+1], h2[q*4+2], h2[q*4+3]);
        }
    }
}

// ---- pass 6: layer-2 aggregate (4 lanes/edge, float4) + fused epilogue ----
__global__ __launch_bounds__(AGT)
void p_agg2(const uint* __restrict__ part, const uint* __restrict__ bBase,
            const uint* __restrict__ bCnt, const float* __restrict__ g,
            const float* __restrict__ dinv,
            const float* __restrict__ b2, const float* __restrict__ Wf,
            const float* __restrict__ bf,
            float* __restrict__ out, int n) {
    __shared__ float acc[PSIZE][HID + 1];   // +1 pad: breaks bank conflicts
    int b = blockIdx.x, t = threadIdx.x;
    // init: self-loop contribution g[node]; 512 threads, float4 each
    if (t < PSIZE * 4) {
        int r = t >> 2, q = t & 3;
        int node = b * PSIZE + r;
        if (node < n) {
            float4 v = *(const float4*)(g + (size_t)node * HID + 4 * q);
            acc[r][q*4+0] = v.x; acc[r][q*4+1] = v.y;
            acc[r][q*4+2] = v.z; acc[r][q*4+3] = v.w;
        } else {
            acc[r][q*4+0] = 0.0f; acc[r][q*4+1] = 0.0f;
            acc[r][q*4+2] = 0.0f; acc[r][q*4+3] = 0.0f;
        }
    }
    __syncthreads();
    uint base = bBase[b], cnt = bCnt[b];
    int gi = t >> 2;        // 256 edge-groups of 4 lanes
    int sub = t & 3;        // this lane's float4 slot within the row
    for (uint i = base + gi; i < base + cnt; i += AGT / 4) {
        uint w = part[i];                    // broadcast within 4-lane group
        uint src = w & SRCMASK;
        uint dl = w >> SRCBITS;
        float4 v = *(const float4*)(g + (size_t)src * HID + 4 * sub);  // 16B/lane, 64B/edge
        atomicAdd(&acc[dl][sub*4+0], v.x);
        atomicAdd(&acc[dl][sub*4+1], v.y);
        atomicAdd(&acc[dl][sub*4+2], v.z);
        atomicAdd(&acc[dl][sub*4+3], v.w);
    }
    __syncthreads();
    if (t < PSIZE) {
        int node = b * PSIZE + t;
        if (node < n) {
            float d = dinv[node];
            float o = bf[0];
#pragma unroll
            for (int j = 0; j < HID; ++j) {
                float h = fmaxf(fmaf(d, acc[t][j], b2[j]), 0.0f);
                o = fmaf(h, Wf[j], o);
            }
            out[node] = tanhf(o);
        }
    }
}

// ============================= fallback (atomic) path =============================

__global__ void f_init_deg(float* deg, int n) {
    int i = blockIdx.x * blockDim.x + threadIdx.x;
    if (i < n) deg[i] = 1.0f;
}

__global__ void f_deg_accum(const int* __restrict__ dstA, float* deg, int e) {
    int i = blockIdx.x * blockDim.x + threadIdx.x;
    if (i < e) atomicAdd(&deg[dstA[i]], 1.0f);
}

__global__ void f_dinv_s(const float* __restrict__ x, float* deg_dinv, float* s, int n) {
    int i = blockIdx.x * blockDim.x + threadIdx.x;
    if (i < n) {
        float d = rsqrtf(deg_dinv[i]);
        deg_dinv[i] = d;
        s[i] = x[i] * d * d;
    }
}

__global__ void f_s_edge(const int* __restrict__ srcA, const int* __restrict__ dstA,
                         const float* __restrict__ x, const float* __restrict__ dinv,
                         float* s, int e) {
    int i = blockIdx.x * blockDim.x + threadIdx.x;
    if (i < e) {
        int si = srcA[i], di = dstA[i];
        atomicAdd(&s[di], x[si] * dinv[si] * dinv[di]);
    }
}

__global__ void f_node_mlp(const float* __restrict__ s, const float* __restrict__ dinv,
                           const float* __restrict__ W1, const float* __restrict__ b1,
                           const float* __restrict__ W2,
                           float* __restrict__ h2pre, float* __restrict__ agg2, int n) {
    int i = blockIdx.x * blockDim.x + threadIdx.x;
    if (i >= n) return;
    float sv = s[i];
    float h1[HID];
#pragma unroll
    for (int j = 0; j < HID; ++j)
        h1[j] = fmaxf(sv * W1[j] + b1[j], 0.0f);
    float d2 = dinv[i] * dinv[i];
    float h2[HID];
#pragma unroll
    for (int k = 0; k < HID; ++k) {
        float acc = 0.0f;
#pragma unroll
        for (int j = 0; j < HID; ++j)
            acc = fmaf(h1[j], W2[j * HID + k], acc);
        h2[k] = acc;
    }
    float4* hp = (float4*)(h2pre + (size_t)i * HID);
    float4* ap = (float4*)(agg2 + (size_t)i * HID);
#pragma unroll
    for (int q = 0; q < 4; ++q) {
        float4 v = make_float4(h2[q*4+0], h2[q*4+1], h2[q*4+2], h2[q*4+3]);
        hp[q] = v;
        ap[q] = make_float4(v.x * d2, v.y * d2, v.z * d2, v.w * d2);
    }
}

__global__ void f_agg_edge(const int* __restrict__ srcA, const int* __restrict__ dstA,
                           const float* __restrict__ dinv,
                           const float* __restrict__ h2pre,
                           float* __restrict__ agg2, int e) {
    int gid = blockIdx.x * blockDim.x + threadIdx.x;
    int ei = gid >> 4;
    int j  = gid & 15;
    if (ei < e) {
        int si = srcA[ei], di = dstA[ei];
        float w = dinv[si] * dinv[di];
        atomicAdd(&agg2[(size_t)di * HID + j], h2pre[(size_t)si * HID + j] * w);
    }
}

__global__ void f_out(const float* __restrict__ agg2, const float* __restrict__ b2,
                      const float* __restrict__ Wf, const float* __restrict__ bf,
                      float* __restrict__ out, int n) {
    int i = blockIdx.x * blockDim.x + threadIdx.x;
    if (i >= n) return;
    float acc = bf[0];
#pragma unroll
    for (int k = 0; k < HID; ++k) {
        float h = fmaxf(agg2[(size_t)i * HID + k] + b2[k], 0.0f);
        acc = fmaf(h, Wf[k], acc);
    }
    out[i] = tanhf(acc);
}

// ============================= launch =============================

extern "C" void kernel_launch(void* const* d_in, const int* in_sizes, int n_in,
                              void* d_out, int out_size, void* d_ws, size_t ws_size,
                              hipStream_t stream) {
    const float* x  = (const float*)d_in[0];
    const int*   ei = (const int*)d_in[1];
    const float* W1 = (const float*)d_in[2];
    const float* b1 = (const float*)d_in[3];
    const float* W2 = (const float*)d_in[4];
    const float* b2 = (const float*)d_in[5];
    const float* Wf = (const float*)d_in[6];
    const float* bf = (const float*)d_in[7];
    float* out = (float*)d_out;

    const int N = in_sizes[0];
    const int E = in_sizes[1] / 2;
    const int* srcA = ei;
    const int* dstA = ei + E;
    (void)n_in; (void)out_size;

    const int NB = (N + PMASK) >> PSHIFT;
    const int B = 256;
    int nb_n = (N + B - 1) / B;
    int nb_e = (E + B - 1) / B;
    int tiles = (E + TILE - 1) / TILE;

    // fast-path ws layout
    size_t off = 0;
    auto takeo = [&](size_t bytes) -> size_t {
        size_t p = off;
        off = (off + bytes + 255) & ~(size_t)255;
        return p;
    };
    size_t o_cntp = takeo((size_t)NB * PAD * 4);
    size_t o_curp = takeo((size_t)NB * PAD * 4);
    size_t o_bb   = takeo((size_t)NB * 4);
    size_t o_bc   = takeo((size_t)NB * 4);
    size_t o_dinv = takeo((size_t)N * 4);
    size_t o_y    = takeo((size_t)N * 4);
    size_t o_part = takeo((size_t)E * 4);
    size_t o_g    = takeo((size_t)N * HID * 4);
    size_t need = off;

    if (N <= (1 << SRCBITS) && ws_size >= need) {
        char* ws = (char*)d_ws;
        uint*  cntPad    = (uint*)(ws + o_cntp);
        uint*  cursorPad = (uint*)(ws + o_curp);
        uint*  bBase     = (uint*)(ws + o_bb);
        uint*  bCnt      = (uint*)(ws + o_bc);
        float* dinv      = (float*)(ws + o_dinv);
        float* y         = (float*)(ws + o_y);
        uint*  part      = (uint*)(ws + o_part);
        float* g         = (float*)(ws + o_g);

        hipMemsetAsync(cntPad, 0, (size_t)NB * PAD * 4, stream);
        hipLaunchKernelGGL(p_bcount, dim3(tiles), dim3(B), 0, stream, dstA, cntPad, E, NB);
        hipLaunchKernelGGL(p_bscan,  dim3(1), dim3(B), 0, stream, cntPad, cursorPad, bBase, bCnt, NB);
        hipLaunchKernelGGL(p_part,   dim3(tiles), dim3(B), 0, stream, srcA, dstA, cursorPad, part, E, NB);
        hipLaunchKernelGGL(p_degy,   dim3(NB), dim3(AGT), 0, stream, part, bBase, bCnt, x, dinv, y, N);
        hipLaunchKernelGGL(p_agg1,   dim3(NB), dim3(AGT), 0, stream, part, bBase, bCnt, y, dinv, W1, b1, W2, g, N);
        hipLaunchKernelGGL(p_agg2,   dim3(NB), dim3(AGT), 0, stream, part, bBase, bCnt, g, dinv, b2, Wf, bf, out, N);
    } else {
        // fallback: known-good atomic path
        size_t foff = 0;
        auto ftake = [&](size_t bytes) -> size_t {
            size_t p = foff;
            foff = (foff + bytes + 255) & ~(size_t)255;
            return p;
        };
        char* ws = (char*)d_ws;
        float* dinv  = (float*)(ws + ftake((size_t)N * 4));
        float* s     = (float*)(ws + ftake((size_t)N * 4));
        float* h2pre = (float*)(ws + ftake((size_t)N * HID * 4));
        float* agg2  = (float*)(ws + ftake((size_t)N * HID * 4));

        long long totD = (long long)E * HID;
        int nb_d = (int)((totD + B - 1) / B);

        hipLaunchKernelGGL(f_init_deg,  dim3(nb_n), dim3(B), 0, stream, dinv, N);
        hipLaunchKernelGGL(f_deg_accum, dim3(nb_e), dim3(B), 0, stream, dstA, dinv, E);
        hipLaunchKernelGGL(f_dinv_s,    dim3(nb_n), dim3(B), 0, stream, x, dinv, s, N);
        hipLaunchKernelGGL(f_s_edge,    dim3(nb_e), dim3(B), 0, stream, srcA, dstA, x, dinv, s, E);
        hipLaunchKernelGGL(f_node_mlp,  dim3(nb_n), dim3(B), 0, stream,
                           s, dinv, W1, b1, W2, h2pre, agg2, N);
        hipLaunchKernelGGL(f_agg_edge,  dim3(nb_d), dim3(B), 0, stream,
                           srcA, dstA, dinv, h2pre, agg2, E);
        hipLaunchKernelGGL(f_out,       dim3(nb_n), dim3(B), 0, stream,
                           agg2, b2, Wf, bf, out, N);
    }
}